// Round 6
// baseline (151.824 us; speedup 1.0000x reference)
//
#include <hip/hip_runtime.h>
#include <math.h>

// QuanvolutionPlus fused, round 6.
// vs round 5 (~28us kernel; latency-bound, no pipe >45%, 16 waves/CU):
//  - W no longer staged to LDS per block: a prologue kernel converts lin_w
//    f32->f16 into d_ws every call (graph-safe, same work each replay); main
//    kernel reads W chunks from global (coalesced 8B/lane, 15.7KB L1-resident).
//  - LDS = scls only (12.7KB/block); NO __syncthreads in the main kernel --
//    the scls exchange is intra-wave (half-wave writes, same half-wave reads),
//    ordered by s_waitcnt lgkmcnt(0) (pattern validated in round 2).
//  - __launch_bounds__(256,6): 24 waves/CU target (was 16).
//  - compute structure (packed-f16 conv+quantum, fdot2 matvec, DPP reduce)
//    unchanged from round 5 (passed, absmax 0.031).

#define NW 4                 // waves per block; 2 samples per wave
#define SCLS_STRIDE 794      // f16 elems per sample; odd word count de-phases halves

typedef __fp16 h2 __attribute__((ext_vector_type(2)));
typedef __fp16 h4 __attribute__((ext_vector_type(4)));

#define FDOT2(a, b, c) __builtin_amdgcn_fdot2((a), (b), (c), false)
#define PK(a, b) __builtin_amdgcn_cvt_pkrtz((a), (b))

__device__ __forceinline__ unsigned h2u(h2 v) { return __builtin_bit_cast(unsigned, v); }
__device__ __forceinline__ h2 uh2(unsigned v) { return __builtin_bit_cast(h2, v); }

// 32-lane segmented sum; returns {sum lanes0-31, sum lanes32-63}
__device__ __forceinline__ float2 red32x2(float x) {
    int v;
    v = __builtin_amdgcn_update_dpp(0, __float_as_int(x), 0x111, 0xf, 0xf, true); x += __int_as_float(v);
    v = __builtin_amdgcn_update_dpp(0, __float_as_int(x), 0x112, 0xf, 0xf, true); x += __int_as_float(v);
    v = __builtin_amdgcn_update_dpp(0, __float_as_int(x), 0x114, 0xf, 0xf, true); x += __int_as_float(v);
    v = __builtin_amdgcn_update_dpp(0, __float_as_int(x), 0x118, 0xf, 0xf, true); x += __int_as_float(v);
    v = __builtin_amdgcn_update_dpp(0, __float_as_int(x), 0x142, 0xa, 0xf, true); x += __int_as_float(v);
    float2 r;
    r.x = __int_as_float(__builtin_amdgcn_readlane(__float_as_int(x), 31));
    r.y = __int_as_float(__builtin_amdgcn_readlane(__float_as_int(x), 63));
    return r;
}

// 3x3 stride-2 conv window for patch (i,j); a[0..8] row-major, halo-masked
__device__ __forceinline__ void load_patch(const float* __restrict__ xs,
                                           unsigned i, int j, float* a) {
    int omid = (int)(2 * i) * 28 + 2 * j;
    float2 Rm = *(const float2*)(xs + omid);                 // a11 a12
    float2 Rb = *(const float2*)(xs + omid + 28);            // a21 a22
    int ot = omid - 28; ot = (ot > 0) ? ot : 0;
    float2 Rt = *(const float2*)(xs + ot);                   // a01 a02
    int olt = omid - 30; olt = (olt > 0) ? olt : 0;
    float2 Lt = *(const float2*)(xs + olt);                  // .y = a00
    int olm = omid - 2; olm = (olm > 0) ? olm : 0;
    float2 Lm = *(const float2*)(xs + olm);                  // .y = a10
    float2 Lb = *(const float2*)(xs + olm + 28);             // .y = a20
    float mt = (i > 0) ? 1.f : 0.f;
    float ml = (j > 0) ? 1.f : 0.f;
    a[0] = Lt.y * (mt * ml); a[1] = Rt.x * mt; a[2] = Rt.y * mt;
    a[3] = Lm.y * ml;        a[4] = Rm.x;      a[5] = Rm.y;
    a[6] = Lb.y * ml;        a[7] = Rb.x;      a[8] = Rb.y;
}

// prologue: lin_w f32 -> f16 into d_ws (1960 float4 -> 1960 h4)
__global__ void w_to_f16(const float* __restrict__ lin_w, __fp16* __restrict__ w16) {
    int i = blockIdx.x * 256 + threadIdx.x;
    if (i < 1960) {
        float4 v = ((const float4*)lin_w)[i];
        h2 a = PK(v.x, v.y);
        h2 b = PK(v.z, v.w);
        h4 w4 = { a.x, a.y, b.x, b.y };
        *(h4*)&w16[4 * i] = w4;
    }
}

__global__ __launch_bounds__(256, 6)
void quanv_fused(const float* __restrict__ x,
                 const float* __restrict__ conv_w,
                 const float* __restrict__ bn_gamma,
                 const float* __restrict__ bn_beta,
                 const float* __restrict__ bn_mean,
                 const float* __restrict__ bn_var,
                 const float* __restrict__ var_params,
                 const __fp16* __restrict__ w16,
                 const float* __restrict__ lin_b,
                 float* __restrict__ out, int B)
{
    __shared__ __align__(16) __fp16 sclsAll[NW * 2 * SCLS_STRIDE]; // 12704 B

    const int tid  = threadIdx.x;
    const int wave = tid >> 6;
    const int lane = tid & 63;
    const int half = lane >> 5;
    const int l32  = lane & 31;

    const int s  = blockIdx.x * (NW * 2) + wave * 2 + half;
    const int sc = (s < B) ? s : (B - 1);
    const float* xs = x + (size_t)sc * 784;
    __fp16* myscls = &sclsAll[(wave * 2 + half) * SCLS_STRIDE];

    // ---- uniform params: BN-folded packed conv weights, packed rotations ----
    h2 w2[36];
    h2 addc2[4];
    #pragma unroll
    for (int c = 0; c < 4; ++c) {
        float iv = bn_gamma[c] * rsqrtf(bn_var[c] + 1e-5f);
        float ac = bn_beta[c] - bn_mean[c] * iv;
        addc2[c] = PK(ac, ac);
        #pragma unroll
        for (int k = 0; k < 9; ++k) {
            float wf = conv_w[c * 9 + k] * iv;
            w2[c * 9 + k] = PK(wf, wf);
        }
    }
    h2 cv2[4], sv2[4];
    #pragma unroll
    for (int k = 0; k < 4; ++k) {
        float sk, ck;
        __sincosf(var_params[k] * 0.5f, &sk, &ck);
        cv2[k] = PK(ck, ck);
        sv2[k] = PK(sk, sk);
    }

    // ---- paired patch loop: patches (l32+64tt, l32+64tt+32) ----
    h2 qh[7][2];
    #pragma unroll
    for (int tt = 0; tt < 4; ++tt) {
        const int tA = 2 * tt, tB = 2 * tt + 1;
        int pA = l32 + 32 * tA, pB = l32 + 32 * tB;
        bool actA = (pA < 196), actB = (pB < 196);
        int pcA = actA ? pA : 195, pcB = actB ? pB : 195;
        unsigned iA = (unsigned)pcA / 14u; int jA = pcA - (int)iA * 14;
        unsigned iB = (unsigned)pcB / 14u; int jB = pcB - (int)iB * 14;

        float aA[9], aB[9];
        load_patch(xs, iA, jA, aA);
        load_patch(xs, iB, jB, aB);

        // conv: 4ch x 9 pk_fma over the patch pair, BN folded
        h2 apk[9];
        #pragma unroll
        for (int k = 0; k < 9; ++k) apk[k] = PK(aA[k], aB[k]);
        const h2 hz = { (__fp16)0.f, (__fp16)0.f };
        #pragma unroll
        for (int c = 0; c < 4; ++c) {
            h2 acc = addc2[c];
            #pragma unroll
            for (int k = 0; k < 9; ++k) acc += w2[c * 9 + k] * apk[k];
            acc = __builtin_elementwise_max(acc, hz);
            if (actA) myscls[c * 196 + pcA] = acc.x;
            if (actB) myscls[c * 196 + pcB] = acc.y;
        }

        // quantum: f32 sincos/encoding, packed-f16 rotation chain
        float haA = 0.5f * (aA[4] + aA[7]), hbA = 0.5f * (aA[5] + aA[8]);
        float haB = 0.5f * (aB[4] + aB[7]), hbB = 0.5f * (aB[5] + aB[8]);
        float c0A, s0A, c1A, s1A, c0B, s0B, c1B, s1B;
        __sincosf(haA, &s0A, &c0A); __sincosf(hbA, &s1A, &c1A);
        __sincosf(haB, &s0B, &c0B); __sincosf(hbB, &s1B, &c1B);
        h2 M00 = PK(c0A * c1A, c0B * c1B);
        h2 M01 = PK(c0A * s1A, c0B * s1B);
        h2 M10 = PK(s0A * s1A, s0B * s1B);
        h2 M11 = PK(s0A * c1A, s0B * c1B);
        h2 T00 = cv2[0] * M00 - sv2[0] * M10;
        h2 T01 = cv2[0] * M01 - sv2[0] * M11;
        h2 T10 = sv2[0] * M00 + cv2[0] * M10;
        h2 T11 = sv2[0] * M01 + cv2[0] * M11;
        h2 U00 = cv2[1] * T00 - sv2[1] * T01;
        h2 U01 = sv2[1] * T00 + cv2[1] * T01;
        h2 U10 = cv2[1] * T10 - sv2[1] * T11;
        h2 U11 = sv2[1] * T10 + cv2[1] * T11;
        h2 V01 = U11, V11 = U01;                 // CNOT(1->0)
        h2 P00 = cv2[2] * U00 - sv2[2] * U10;
        h2 P01 = cv2[2] * V01 - sv2[2] * V11;
        h2 P10 = sv2[2] * U00 + cv2[2] * U10;
        h2 P11 = sv2[2] * V01 + cv2[2] * V11;
        h2 Q00 = cv2[3] * P00 - sv2[3] * P01;
        h2 Q01 = sv2[3] * P00 + cv2[3] * P01;
        h2 Q10 = cv2[3] * P10 - sv2[3] * P11;
        h2 Q11 = sv2[3] * P10 + cv2[3] * P11;
        h2 sq00 = Q00 * Q00, sq01 = Q01 * Q01, sq10 = Q10 * Q10, sq11 = Q11 * Q11;
        h2 z0 = (sq00 + sq01) - (sq10 + sq11);
        h2 z1 = (sq00 + sq10) - (sq01 + sq11);
        h2 x0 = Q00 * Q10 + Q01 * Q11; x0 = x0 + x0;
        h2 x1 = Q00 * Q01 + Q10 * Q11; x1 = x1 + x1;

        unsigned z0u = h2u(z0), z1u = h2u(z1), x0u = h2u(x0), x1u = h2u(x1);
        qh[tA][0] = uh2(__builtin_amdgcn_perm(z1u, z0u, 0x05040100));
        qh[tA][1] = uh2(__builtin_amdgcn_perm(x1u, x0u, 0x05040100));
        if (tB < 7) {
            qh[tB][0] = uh2(__builtin_amdgcn_perm(z1u, z0u, 0x07060302));
            qh[tB][1] = uh2(__builtin_amdgcn_perm(x1u, x0u, 0x07060302));
        }
    }

    // intra-wave scls visibility (writer lanes and reader lanes share the wave)
    asm volatile("s_waitcnt lgkmcnt(0)" ::: "memory");

    // ---- fused matvec in f16, W chunks from global (L1-resident 15.7KB) ----
    float ps[10];
    #pragma unroll
    for (int o = 0; o < 10; ++o) ps[o] = 0.f;

    const h4* gw = (const h4*)w16;   // gw[o*196 + p] = w[o][4p..4p+3]
    const h2 hz = { (__fp16)0.f, (__fp16)0.f };
    #pragma unroll
    for (int t = 0; t < 7; ++t) {
        int p = l32 + 32 * t;
        bool act = (p < 196);
        int pc = act ? p : 195;
        h4 cl4 = *(const h4*)&myscls[4 * pc];
        h2 c0 = __builtin_shufflevector(cl4, cl4, 0, 1);
        h2 c1 = __builtin_shufflevector(cl4, cl4, 2, 3);
        h2 f0 = c0 + qh[t][0];
        h2 f1 = c1 + qh[t][1];
        f0 = act ? f0 : hz;
        f1 = act ? f1 : hz;
        #pragma unroll
        for (int o = 0; o < 10; ++o) {
            h4 wv = gw[o * 196 + pc];
            h2 wlo = __builtin_shufflevector(wv, wv, 0, 1);
            h2 whi = __builtin_shufflevector(wv, wv, 2, 3);
            ps[o] = FDOT2(f0, wlo, ps[o]);
            ps[o] = FDOT2(f1, whi, ps[o]);
        }
    }

    // ---- reduce both halves; softmax; store ----
    float lg[10];
    #pragma unroll
    for (int o = 0; o < 10; ++o) {
        float2 r = red32x2(ps[o]);
        lg[o] = (half ? r.y : r.x) + lin_b[o];
    }

    float mx = lg[0];
    #pragma unroll
    for (int o = 1; o < 10; ++o) mx = fmaxf(mx, lg[o]);
    float se = 0.f;
    #pragma unroll
    for (int o = 0; o < 10; ++o) se += __expf(lg[o] - mx);
    float ls = __logf(se);

    if (l32 < 10 && s < B) {
        float v = lg[0];
        #pragma unroll
        for (int o = 1; o < 10; ++o) v = (l32 == o) ? lg[o] : v;
        out[(size_t)s * 10 + l32] = v - mx - ls;
    }
}

extern "C" void kernel_launch(void* const* d_in, const int* in_sizes, int n_in,
                              void* d_out, int out_size, void* d_ws, size_t ws_size,
                              hipStream_t stream) {
    const float* x          = (const float*)d_in[0];
    const float* conv_w     = (const float*)d_in[1];
    const float* bn_gamma   = (const float*)d_in[2];
    const float* bn_beta    = (const float*)d_in[3];
    const float* bn_mean    = (const float*)d_in[4];
    const float* bn_var     = (const float*)d_in[5];
    const float* var_params = (const float*)d_in[6];
    const float* lin_w      = (const float*)d_in[7];
    const float* lin_b      = (const float*)d_in[8];
    float* out = (float*)d_out;
    __fp16* w16 = (__fp16*)d_ws;   // 15680 B used

    const int B = in_sizes[0] / 784;

    w_to_f16<<<8, 256, 0, stream>>>(lin_w, w16);

    const int blocks = (B + NW * 2 - 1) / (NW * 2);
    quanv_fused<<<blocks, 256, 0, stream>>>(x, conv_w, bn_gamma, bn_beta, bn_mean,
                                            bn_var, var_params, w16, lin_b, out, B);
}

// Round 7
// 126.463 us; speedup vs baseline: 1.2005x; 1.2005x over previous
//
#include <hip/hip_runtime.h>
#include <math.h>

// QuanvolutionPlus fused, round 7.
// Round 6 post-mortem: __launch_bounds__(256,6) + packed-f16 constant arrays
// (w2[36] etc, ~100 live VGPRs) forced scratch spills (VGPR capped at 40,
// WRITE_SIZE 640KB -> 47.7MB) -> 67us. Fix: keep round-6 STRUCTURE
// (scls-only LDS 12.7KB, no __syncthreads, prologue f16 W, matvec from global)
// but round-4 COMPUTE (f32 scalar conv+quantum; uniform conv/rot params live
// in SGPRs, costing no VGPRs -- round 2 measured 52 VGPR with this pattern).
// __launch_bounds__(256,5): VGPR cap ~102 (no spill), 20 waves/CU.
//
// Index facts (verified r1-r2): cls flat n = c*196+p ; q flat n = 4p+k ;
// logits[o] = sum_n fused[n]*lin_w[o*784+n] + lin_b[o].

#define NW 4                 // waves per block; 2 samples per wave
#define SCLS_STRIDE 794      // f16 elems per sample; odd word count de-phases halves

typedef __fp16 h2 __attribute__((ext_vector_type(2)));
typedef __fp16 h4 __attribute__((ext_vector_type(4)));

#define FDOT2(a, b, c) __builtin_amdgcn_fdot2((a), (b), (c), false)
#define PK(a, b) __builtin_amdgcn_cvt_pkrtz((a), (b))

// 32-lane segmented sum; returns {sum lanes0-31, sum lanes32-63}
__device__ __forceinline__ float2 red32x2(float x) {
    int v;
    v = __builtin_amdgcn_update_dpp(0, __float_as_int(x), 0x111, 0xf, 0xf, true); x += __int_as_float(v);
    v = __builtin_amdgcn_update_dpp(0, __float_as_int(x), 0x112, 0xf, 0xf, true); x += __int_as_float(v);
    v = __builtin_amdgcn_update_dpp(0, __float_as_int(x), 0x114, 0xf, 0xf, true); x += __int_as_float(v);
    v = __builtin_amdgcn_update_dpp(0, __float_as_int(x), 0x118, 0xf, 0xf, true); x += __int_as_float(v);
    v = __builtin_amdgcn_update_dpp(0, __float_as_int(x), 0x142, 0xa, 0xf, true); x += __int_as_float(v);
    float2 r;
    r.x = __int_as_float(__builtin_amdgcn_readlane(__float_as_int(x), 31));
    r.y = __int_as_float(__builtin_amdgcn_readlane(__float_as_int(x), 63));
    return r;
}

// prologue: lin_w f32 -> f16 into d_ws (1960 float4 -> 1960 h4)
__global__ void w_to_f16(const float* __restrict__ lin_w, __fp16* __restrict__ w16) {
    int i = blockIdx.x * 256 + threadIdx.x;
    if (i < 1960) {
        float4 v = ((const float4*)lin_w)[i];
        h2 a = PK(v.x, v.y);
        h2 b = PK(v.z, v.w);
        h4 w4 = { a.x, a.y, b.x, b.y };
        *(h4*)&w16[4 * i] = w4;
    }
}

__global__ __launch_bounds__(256, 5)
void quanv_fused(const float* __restrict__ x,
                 const float* __restrict__ conv_w,
                 const float* __restrict__ bn_gamma,
                 const float* __restrict__ bn_beta,
                 const float* __restrict__ bn_mean,
                 const float* __restrict__ bn_var,
                 const float* __restrict__ var_params,
                 const __fp16* __restrict__ w16,
                 const float* __restrict__ lin_b,
                 float* __restrict__ out, int B)
{
    __shared__ __align__(16) __fp16 sclsAll[NW * 2 * SCLS_STRIDE]; // 12704 B

    const int tid  = threadIdx.x;
    const int wave = tid >> 6;
    const int lane = tid & 63;
    const int half = lane >> 5;
    const int l32  = lane & 31;

    const int s  = blockIdx.x * (NW * 2) + wave * 2 + half;
    const int sc = (s < B) ? s : (B - 1);
    const float* xs = x + (size_t)sc * 784;
    __fp16* myscls = &sclsAll[(wave * 2 + half) * SCLS_STRIDE];

    // ---- uniform params (scalar loads -> SGPRs; BN folded into conv weights) ----
    float w[36], addc[4];
    #pragma unroll
    for (int c = 0; c < 4; ++c) {
        float iv = bn_gamma[c] * rsqrtf(bn_var[c] + 1e-5f);
        addc[c] = bn_beta[c] - bn_mean[c] * iv;
        #pragma unroll
        for (int k = 0; k < 9; ++k) w[c * 9 + k] = conv_w[c * 9 + k] * iv;
    }
    float cv[4], sv[4];
    #pragma unroll
    for (int k = 0; k < 4; ++k) __sincosf(var_params[k] * 0.5f, &sv[k], &cv[k]);

    // ---- per-patch loop: conv(4ch)+BN+ReLU -> scls(f16); quantum -> qh regs ----
    h2 qh[7][2];
    #pragma unroll
    for (int t = 0; t < 7; ++t) {
        int p = l32 + 32 * t;
        bool act = (p < 196);
        int pc = act ? p : 195;
        unsigned i = (unsigned)pc / 14u;
        int j = pc - (int)i * 14;
        int omid = (int)(2 * i) * 28 + 2 * j;

        // 6 aligned float2 loads; clamped offsets stay in [0,783]
        float2 Rm = *(const float2*)(xs + omid);                 // a11 a12
        float2 Rb = *(const float2*)(xs + omid + 28);            // a21 a22
        int ot = omid - 28; ot = (ot > 0) ? ot : 0;
        float2 Rt = *(const float2*)(xs + ot);                   // a01 a02
        int olt = omid - 30; olt = (olt > 0) ? olt : 0;
        float2 Lt = *(const float2*)(xs + olt);                  // .y = a00
        int olm = omid - 2; olm = (olm > 0) ? olm : 0;
        float2 Lm = *(const float2*)(xs + olm);                  // .y = a10
        float2 Lb = *(const float2*)(xs + olm + 28);             // .y = a20

        float mt = (i > 0) ? 1.f : 0.f;
        float ml = (j > 0) ? 1.f : 0.f;
        float a00 = Lt.y * (mt * ml), a01 = Rt.x * mt, a02 = Rt.y * mt;
        float a10 = Lm.y * ml,        a11 = Rm.x,      a12 = Rm.y;
        float a20 = Lb.y * ml,        a21 = Rb.x,      a22 = Rb.y;

        if (act) {
            #pragma unroll
            for (int c = 0; c < 4; ++c) {
                float h = addc[c]
                        + w[c*9+0]*a00 + w[c*9+1]*a01 + w[c*9+2]*a02
                        + w[c*9+3]*a10 + w[c*9+4]*a11 + w[c*9+5]*a12
                        + w[c*9+6]*a20 + w[c*9+7]*a21 + w[c*9+8]*a22;
                myscls[c * 196 + pc] = (__fp16)fmaxf(h, 0.f);
            }
        }

        // quantum over patch pixels a11 a12 a21 a22 (f32 scalar)
        float ha = 0.5f * (a11 + a21);
        float hb = 0.5f * (a12 + a22);
        float c0, s0, c1, s1;
        __sincosf(ha, &s0, &c0);
        __sincosf(hb, &s1, &c1);
        float m00 = c0*c1, m01 = c0*s1;
        float m10 = s0*s1, m11 = s0*c1;                                  // enc + CNOT(0->1)
        float t00 = cv[0]*m00 - sv[0]*m10, t01 = cv[0]*m01 - sv[0]*m11;
        float t10 = sv[0]*m00 + cv[0]*m10, t11 = sv[0]*m01 + cv[0]*m11;  // RY(v0) w0
        float u00 = cv[1]*t00 - sv[1]*t01, u01 = sv[1]*t00 + cv[1]*t01;
        float u10 = cv[1]*t10 - sv[1]*t11, u11 = sv[1]*t10 + cv[1]*t11;  // RY(v1) w1
        float tmp = u01; u01 = u11; u11 = tmp;                            // CNOT(1->0)
        float p00 = cv[2]*u00 - sv[2]*u10, p01 = cv[2]*u01 - sv[2]*u11;
        float p10 = sv[2]*u00 + cv[2]*u10, p11 = sv[2]*u01 + cv[2]*u11;  // RY(v2) w0
        float q00 = cv[3]*p00 - sv[3]*p01, q01 = sv[3]*p00 + cv[3]*p01;
        float q10 = cv[3]*p10 - sv[3]*p11, q11 = sv[3]*p10 + cv[3]*p11;  // RY(v3) w1

        float z0 = q00*q00 + q01*q01 - q10*q10 - q11*q11;
        float z1 = q00*q00 + q10*q10 - q01*q01 - q11*q11;
        float x0 = 2.f * (q00*q10 + q01*q11);
        float x1 = 2.f * (q00*q01 + q10*q11);
        qh[t][0] = PK(z0, z1);
        qh[t][1] = PK(x0, x1);
    }

    // intra-wave scls visibility (writer lanes and reader lanes share the wave)
    asm volatile("s_waitcnt lgkmcnt(0)" ::: "memory");

    // ---- fused matvec in f16, W chunks from global (15.7KB, L1-resident) ----
    float ps[10];
    #pragma unroll
    for (int o = 0; o < 10; ++o) ps[o] = 0.f;

    const h4* gw = (const h4*)w16;   // gw[o*196 + p] = w[o][4p..4p+3]
    const h2 hz = { (__fp16)0.f, (__fp16)0.f };
    #pragma unroll
    for (int t = 0; t < 7; ++t) {
        int p = l32 + 32 * t;
        bool act = (p < 196);
        int pc = act ? p : 195;
        h4 cl4 = *(const h4*)&myscls[4 * pc];
        h2 c0 = __builtin_shufflevector(cl4, cl4, 0, 1);
        h2 c1 = __builtin_shufflevector(cl4, cl4, 2, 3);
        h2 f0 = c0 + qh[t][0];
        h2 f1 = c1 + qh[t][1];
        f0 = act ? f0 : hz;
        f1 = act ? f1 : hz;
        #pragma unroll
        for (int o = 0; o < 10; ++o) {
            h4 wv = gw[o * 196 + pc];
            h2 wlo = __builtin_shufflevector(wv, wv, 0, 1);
            h2 whi = __builtin_shufflevector(wv, wv, 2, 3);
            ps[o] = FDOT2(f0, wlo, ps[o]);
            ps[o] = FDOT2(f1, whi, ps[o]);
        }
    }

    // ---- reduce both halves; softmax; store ----
    float lg[10];
    #pragma unroll
    for (int o = 0; o < 10; ++o) {
        float2 r = red32x2(ps[o]);
        lg[o] = (half ? r.y : r.x) + lin_b[o];
    }

    float mx = lg[0];
    #pragma unroll
    for (int o = 1; o < 10; ++o) mx = fmaxf(mx, lg[o]);
    float se = 0.f;
    #pragma unroll
    for (int o = 0; o < 10; ++o) se += __expf(lg[o] - mx);
    float ls = __logf(se);

    if (l32 < 10 && s < B) {
        float v = lg[0];
        #pragma unroll
        for (int o = 1; o < 10; ++o) v = (l32 == o) ? lg[o] : v;
        out[(size_t)s * 10 + l32] = v - mx - ls;
    }
}

extern "C" void kernel_launch(void* const* d_in, const int* in_sizes, int n_in,
                              void* d_out, int out_size, void* d_ws, size_t ws_size,
                              hipStream_t stream) {
    const float* x          = (const float*)d_in[0];
    const float* conv_w     = (const float*)d_in[1];
    const float* bn_gamma   = (const float*)d_in[2];
    const float* bn_beta    = (const float*)d_in[3];
    const float* bn_mean    = (const float*)d_in[4];
    const float* bn_var     = (const float*)d_in[5];
    const float* var_params = (const float*)d_in[6];
    const float* lin_w      = (const float*)d_in[7];
    const float* lin_b      = (const float*)d_in[8];
    float* out = (float*)d_out;
    __fp16* w16 = (__fp16*)d_ws;   // 15680 B used

    const int B = in_sizes[0] / 784;

    w_to_f16<<<8, 256, 0, stream>>>(lin_w, w16);

    const int blocks = (B + NW * 2 - 1) / (NW * 2);
    quanv_fused<<<blocks, 256, 0, stream>>>(x, conv_w, bn_gamma, bn_beta, bn_mean,
                                            bn_var, var_params, w16, lin_b, out, B);
}

// Round 8
// 111.418 us; speedup vs baseline: 1.3627x; 1.1350x over previous
//
#include <hip/hip_runtime.h>
#include <math.h>

// QuanvolutionPlus fused, round 8 = round 4 (best known, bench 110.7) + 2 deltas.
// Evidence base:
//  - r7: W-from-global matvec is latency-poison (L1 thrash W+x > 32KB; 55us vs
//    r4's ~27us). W must stay in LDS.
//  - r6: launch_bounds(256,6) + packed-f16 constants spilled (VGPR cap 40). The
//    f32-scalar compute shape compiles to ~48 VGPR (r7), so (256,5) cap=102 is safe.
// Deltas vs round 4:
//  1. __launch_bounds__(256,5): LDS 28.4KB permits 5 blocks/CU; the old bound
//     of 4 waves/EU was the binding constraint. 16 -> 20 waves/CU.
//  2. lwh staged from prologue-converted f16 w16 (d_ws): 4x uint4 copy per
//     thread, no cvt chain at block start.
//
// Index facts (verified r1-r2): cls flat n = c*196+p ; q flat n = 4p+k ;
// logits[o] = sum_n fused[n]*lin_w[o*784+n] + lin_b[o].

#define NW 4                 // waves per block; 2 samples per wave
#define SCLS_STRIDE 794      // f16 elems per sample; odd word count de-phases halves

typedef __fp16 h2 __attribute__((ext_vector_type(2)));
typedef __fp16 h4 __attribute__((ext_vector_type(4)));

#define FDOT2(a, b, c) __builtin_amdgcn_fdot2((a), (b), (c), false)
#define PK(a, b) __builtin_amdgcn_cvt_pkrtz((a), (b))

// 32-lane segmented sum; returns {sum lanes0-31, sum lanes32-63}
__device__ __forceinline__ float2 red32x2(float x) {
    int v;
    v = __builtin_amdgcn_update_dpp(0, __float_as_int(x), 0x111, 0xf, 0xf, true); x += __int_as_float(v);
    v = __builtin_amdgcn_update_dpp(0, __float_as_int(x), 0x112, 0xf, 0xf, true); x += __int_as_float(v);
    v = __builtin_amdgcn_update_dpp(0, __float_as_int(x), 0x114, 0xf, 0xf, true); x += __int_as_float(v);
    v = __builtin_amdgcn_update_dpp(0, __float_as_int(x), 0x118, 0xf, 0xf, true); x += __int_as_float(v);
    v = __builtin_amdgcn_update_dpp(0, __float_as_int(x), 0x142, 0xa, 0xf, true); x += __int_as_float(v);
    float2 r;
    r.x = __int_as_float(__builtin_amdgcn_readlane(__float_as_int(x), 31));
    r.y = __int_as_float(__builtin_amdgcn_readlane(__float_as_int(x), 63));
    return r;
}

// prologue: lin_w f32 -> f16 into d_ws (1960 float4 -> 1960 h4 = 980 uint4)
__global__ void w_to_f16(const float* __restrict__ lin_w, __fp16* __restrict__ w16) {
    int i = blockIdx.x * 256 + threadIdx.x;
    if (i < 1960) {
        float4 v = ((const float4*)lin_w)[i];
        h2 a = PK(v.x, v.y);
        h2 b = PK(v.z, v.w);
        h4 w4 = { a.x, a.y, b.x, b.y };
        *(h4*)&w16[4 * i] = w4;
    }
}

__global__ __launch_bounds__(256, 5)
void quanv_fused(const float* __restrict__ x,
                 const float* __restrict__ conv_w,
                 const float* __restrict__ bn_gamma,
                 const float* __restrict__ bn_beta,
                 const float* __restrict__ bn_mean,
                 const float* __restrict__ bn_var,
                 const float* __restrict__ var_params,
                 const __fp16* __restrict__ w16g,
                 const float* __restrict__ lin_b,
                 float* __restrict__ out, int B)
{
    __shared__ __align__(16) __fp16 lwh[7840];                     // 15680 B
    __shared__ __align__(16) __fp16 sclsAll[NW * 2 * SCLS_STRIDE]; // 12704 B

    const int tid  = threadIdx.x;
    const int wave = tid >> 6;
    const int lane = tid & 63;
    const int half = lane >> 5;
    const int l32  = lane & 31;

    const int s  = blockIdx.x * (NW * 2) + wave * 2 + half;
    const int sc = (s < B) ? s : (B - 1);
    const float* xs = x + (size_t)sc * 784;
    __fp16* myscls = &sclsAll[(wave * 2 + half) * SCLS_STRIDE];

    // ---- stage f16 W (from prologue) -> LDS: plain 16B copy, 980 uint4 ----
    {
        const uint4* src = (const uint4*)w16g;
        uint4* dst = (uint4*)lwh;
        #pragma unroll
        for (int t = 0; t < 4; ++t) {
            int i = tid + t * 256;
            if (i < 980) dst[i] = src[i];
        }
    }

    // ---- uniform params (scalar loads -> SGPRs; BN folded into conv weights) ----
    float w[36], addc[4];
    #pragma unroll
    for (int c = 0; c < 4; ++c) {
        float iv = bn_gamma[c] * rsqrtf(bn_var[c] + 1e-5f);
        addc[c] = bn_beta[c] - bn_mean[c] * iv;
        #pragma unroll
        for (int k = 0; k < 9; ++k) w[c * 9 + k] = conv_w[c * 9 + k] * iv;
    }
    float cv[4], sv[4];
    #pragma unroll
    for (int k = 0; k < 4; ++k) __sincosf(var_params[k] * 0.5f, &sv[k], &cv[k]);

    // ---- per-patch loop: conv(4ch)+BN+ReLU -> scls(f16); quantum -> qh regs ----
    h2 qh[7][2];
    #pragma unroll
    for (int t = 0; t < 7; ++t) {
        int p = l32 + 32 * t;
        bool act = (p < 196);
        int pc = act ? p : 195;
        unsigned i = (unsigned)pc / 14u;
        int j = pc - (int)i * 14;
        int omid = (int)(2 * i) * 28 + 2 * j;

        // 6 aligned float2 loads; clamped offsets stay in [0,783]
        float2 Rm = *(const float2*)(xs + omid);                 // a11 a12
        float2 Rb = *(const float2*)(xs + omid + 28);            // a21 a22
        int ot = omid - 28; ot = (ot > 0) ? ot : 0;
        float2 Rt = *(const float2*)(xs + ot);                   // a01 a02
        int olt = omid - 30; olt = (olt > 0) ? olt : 0;
        float2 Lt = *(const float2*)(xs + olt);                  // .y = a00
        int olm = omid - 2; olm = (olm > 0) ? olm : 0;
        float2 Lm = *(const float2*)(xs + olm);                  // .y = a10
        float2 Lb = *(const float2*)(xs + olm + 28);             // .y = a20

        float mt = (i > 0) ? 1.f : 0.f;
        float ml = (j > 0) ? 1.f : 0.f;
        float a00 = Lt.y * (mt * ml), a01 = Rt.x * mt, a02 = Rt.y * mt;
        float a10 = Lm.y * ml,        a11 = Rm.x,      a12 = Rm.y;
        float a20 = Lb.y * ml,        a21 = Rb.x,      a22 = Rb.y;

        if (act) {
            #pragma unroll
            for (int c = 0; c < 4; ++c) {
                float h = addc[c]
                        + w[c*9+0]*a00 + w[c*9+1]*a01 + w[c*9+2]*a02
                        + w[c*9+3]*a10 + w[c*9+4]*a11 + w[c*9+5]*a12
                        + w[c*9+6]*a20 + w[c*9+7]*a21 + w[c*9+8]*a22;
                myscls[c * 196 + pc] = (__fp16)fmaxf(h, 0.f);
            }
        }

        // quantum over patch pixels a11 a12 a21 a22 (f32 scalar)
        float ha = 0.5f * (a11 + a21);
        float hb = 0.5f * (a12 + a22);
        float c0, s0, c1, s1;
        __sincosf(ha, &s0, &c0);
        __sincosf(hb, &s1, &c1);
        float m00 = c0*c1, m01 = c0*s1;
        float m10 = s0*s1, m11 = s0*c1;                                  // enc + CNOT(0->1)
        float t00 = cv[0]*m00 - sv[0]*m10, t01 = cv[0]*m01 - sv[0]*m11;
        float t10 = sv[0]*m00 + cv[0]*m10, t11 = sv[0]*m01 + cv[0]*m11;  // RY(v0) w0
        float u00 = cv[1]*t00 - sv[1]*t01, u01 = sv[1]*t00 + cv[1]*t01;
        float u10 = cv[1]*t10 - sv[1]*t11, u11 = sv[1]*t10 + cv[1]*t11;  // RY(v1) w1
        float tmp = u01; u01 = u11; u11 = tmp;                            // CNOT(1->0)
        float p00 = cv[2]*u00 - sv[2]*u10, p01 = cv[2]*u01 - sv[2]*u11;
        float p10 = sv[2]*u00 + cv[2]*u10, p11 = sv[2]*u01 + cv[2]*u11;  // RY(v2) w0
        float q00 = cv[3]*p00 - sv[3]*p01, q01 = sv[3]*p00 + cv[3]*p01;
        float q10 = cv[3]*p10 - sv[3]*p11, q11 = sv[3]*p10 + cv[3]*p11;  // RY(v3) w1

        float z0 = q00*q00 + q01*q01 - q10*q10 - q11*q11;
        float z1 = q00*q00 + q10*q10 - q01*q01 - q11*q11;
        float x0 = 2.f * (q00*q10 + q01*q11);
        float x1 = 2.f * (q00*q01 + q10*q11);
        qh[t][0] = PK(z0, z1);
        qh[t][1] = PK(x0, x1);
    }

    __syncthreads();   // lwh staging visible block-wide; orders scls too

    // ---- fused matvec in f16 against LDS lin_w ----
    float ps[10];
    #pragma unroll
    for (int o = 0; o < 10; ++o) ps[o] = 0.f;

    const h2 hz = { (__fp16)0.f, (__fp16)0.f };
    #pragma unroll
    for (int t = 0; t < 7; ++t) {
        int p = l32 + 32 * t;
        bool act = (p < 196);
        int pc = act ? p : 195;
        h4 cl4 = *(const h4*)&myscls[4 * pc];
        h2 c0 = __builtin_shufflevector(cl4, cl4, 0, 1);
        h2 c1 = __builtin_shufflevector(cl4, cl4, 2, 3);
        h2 f0 = c0 + qh[t][0];
        h2 f1 = c1 + qh[t][1];
        f0 = act ? f0 : hz;
        f1 = act ? f1 : hz;
        const __fp16* wbase = &lwh[4 * pc];
        #pragma unroll
        for (int o = 0; o < 10; ++o) {
            h4 wv = *(const h4*)&wbase[o * 784];
            h2 wlo = __builtin_shufflevector(wv, wv, 0, 1);
            h2 whi = __builtin_shufflevector(wv, wv, 2, 3);
            ps[o] = FDOT2(f0, wlo, ps[o]);
            ps[o] = FDOT2(f1, whi, ps[o]);
        }
    }

    // ---- reduce both halves; softmax; store ----
    float lg[10];
    #pragma unroll
    for (int o = 0; o < 10; ++o) {
        float2 r = red32x2(ps[o]);
        lg[o] = (half ? r.y : r.x) + lin_b[o];
    }

    float mx = lg[0];
    #pragma unroll
    for (int o = 1; o < 10; ++o) mx = fmaxf(mx, lg[o]);
    float se = 0.f;
    #pragma unroll
    for (int o = 0; o < 10; ++o) se += __expf(lg[o] - mx);
    float ls = __logf(se);

    if (l32 < 10 && s < B) {
        float v = lg[0];
        #pragma unroll
        for (int o = 1; o < 10; ++o) v = (l32 == o) ? lg[o] : v;
        out[(size_t)s * 10 + l32] = v - mx - ls;
    }
}

extern "C" void kernel_launch(void* const* d_in, const int* in_sizes, int n_in,
                              void* d_out, int out_size, void* d_ws, size_t ws_size,
                              hipStream_t stream) {
    const float* x          = (const float*)d_in[0];
    const float* conv_w     = (const float*)d_in[1];
    const float* bn_gamma   = (const float*)d_in[2];
    const float* bn_beta    = (const float*)d_in[3];
    const float* bn_mean    = (const float*)d_in[4];
    const float* bn_var     = (const float*)d_in[5];
    const float* var_params = (const float*)d_in[6];
    const float* lin_w      = (const float*)d_in[7];
    const float* lin_b      = (const float*)d_in[8];
    float* out = (float*)d_out;
    __fp16* w16 = (__fp16*)d_ws;   // 15680 B used

    const int B = in_sizes[0] / 784;

    w_to_f16<<<8, 256, 0, stream>>>(lin_w, w16);

    const int blocks = (B + NW * 2 - 1) / (NW * 2);
    quanv_fused<<<blocks, 256, 0, stream>>>(x, conv_w, bn_gamma, bn_beta, bn_mean,
                                            bn_var, var_params, w16, lin_b, out, B);
}